// Round 14
// baseline (2103.489 us; speedup 1.0000x reference)
//
#include <hip/hip_runtime.h>

#define BB 512
#define V0 1024
#define V1 256
#define E0 8192
#define E1 2048

// ---------------- CSR build (deterministic) ----------------
__global__ void k_deg(const int* __restrict__ rows, int E, int* __restrict__ deg) {
    int t = blockIdx.x * 256 + threadIdx.x;
    if (t < E) atomicAdd(&deg[rows[t]], 1);
}

__global__ void k_scan(const int* __restrict__ deg, int* __restrict__ off, int V) {
    __shared__ int s[1024];
    int t = threadIdx.x;
    s[t] = (t < V) ? deg[t] : 0;
    __syncthreads();
    for (int d = 1; d < 1024; d <<= 1) {
        int val = (t >= d) ? s[t - d] : 0;
        __syncthreads();
        s[t] += val;
        __syncthreads();
    }
    if (t < V) off[t + 1] = s[t];
    if (t == 0) off[0] = 0;
}

// stable fill: edge e goes to off[row] + (#earlier edges with same row); packed (col,val)
__global__ void k_fillp(const int* __restrict__ rows, const int* __restrict__ cols,
                        const float* __restrict__ vals, int E,
                        const int* __restrict__ off, int2* __restrict__ epk) {
    __shared__ int rs[256];
    int e = blockIdx.x * 256 + threadIdx.x;
    int r = (e < E) ? rows[e] : -1;
    int rank = 0;
    for (int c0 = 0; c0 <= (int)blockIdx.x; ++c0) {
        __syncthreads();
        int idx = c0 * 256 + threadIdx.x;
        rs[threadIdx.x] = (idx < E) ? rows[idx] : -2;
        __syncthreads();
        int lim = e - c0 * 256;
        if (lim > 256) lim = 256;
        for (int j = 0; j < lim; ++j) rank += (rs[j] == r) ? 1 : 0;
    }
    if (e < E) {
        int p = off[r] + rank;
        epk[p] = make_int2(cols[e], __float_as_int(vals[e]));
    }
}

// ---------------- fused cheby conv, batch-major, feature-PAIR-major LDS ----------------
// Base = R13 (verified 474us). Change: slab layout [pair][col][2] (row stride RS=2V+4)
// so edge gathers are ds_read_b64 (FH/2 per edge instead of FH b32). Same bank work,
// half the LDS issue slots on the gather path. GEMM A-reads are b128 pair-quads
// (k=2p,2p+1 x 2 vertices per read). Everything else (Wl panels, int2 edges, 2-deep
// prefetch, acc[4][OW] microtile, OS split, pooled epilogue) unchanged.
template <int V, int FIN, int FH, int FOUT, int OS, int POOL, int MW>
__global__ __launch_bounds__(V * OS, MW) void k_conv(
    const float* __restrict__ xin, const float* __restrict__ W,
    const float* __restrict__ bias, float* __restrict__ out,
    const int* __restrict__ off, const int2* __restrict__ epk) {
    constexpr int NPH = FIN / FH;
    constexpr int FHP = (FH == 3) ? 4 : FH;   // padded per-phase features (even)
    constexpr int FHS = FHP / OS;             // features gathered per thread
    constexpr int PP = FHS / 2;               // pairs per thread
    constexpr int PR = 3 * FHP / 2;           // total pair rows (x0|x1|x2)
    constexpr int RS = 2 * V + 4;             // pair-row stride in floats
    constexpr int OW = FOUT / (4 * OS);       // outputs per thread
    constexpr int NT = V * OS;
    __shared__ float xs[PR * RS];
    __shared__ float Wl[3 * FHP * FOUT];

    const int t = threadIdx.x;
    const int b = blockIdx.x;
    const int os = (OS == 1) ? 0 : (t / V);
    const int vloc = (OS == 1) ? t : (t - os * V);
    const int vt = vloc >> 2;
    const int ot = vloc & 3;
    const int o0 = os * (FOUT / OS) + ot * OW;
    const int fbp = os * PP;                  // pair offset within a term

    const int s0 = off[vloc];
    const int e0 = off[vloc + 1];

    float acc[4][OW];
#pragma unroll
    for (int i = 0; i < 4; ++i)
#pragma unroll
        for (int o = 0; o < OW; ++o) acc[i][o] = 0.f;

// gather pass (2-deep edge prefetch): r = L * slab-pairs[RBP+fbp..) -> [ROUTP+fbp..)
#define GATHER(RBP, ROUTP)                                                    \
    {                                                                         \
        float r_[FHS];                                                        \
        _Pragma("unroll") for (int f = 0; f < FHS; ++f) r_[f] = 0.f;          \
        int2 e_ = epk[s0];                                                    \
        for (int p = s0; p < e0; ++p) {                                       \
            int2 cur_ = e_;                                                   \
            if (p + 1 < e0) e_ = epk[p + 1];                                  \
            float w_ = __int_as_float(cur_.y);                                \
            int c2_ = 2 * cur_.x;                                             \
            _Pragma("unroll") for (int pp = 0; pp < PP; ++pp) {               \
                float2 q_ = *(const float2*)&xs[((RBP) + fbp + pp) * RS + c2_]; \
                r_[2 * pp + 0] += w_ * q_.x;                                  \
                r_[2 * pp + 1] += w_ * q_.y;                                  \
            }                                                                 \
        }                                                                     \
        _Pragma("unroll") for (int pp = 0; pp < PP; ++pp) {                   \
            float2 st_ = {r_[2 * pp + 0], r_[2 * pp + 1]};                    \
            *(float2*)&xs[((ROUTP) + fbp + pp) * RS + 2 * vloc] = st_;        \
        }                                                                     \
    }

    for (int ph = 0; ph < NPH; ++ph) {
        // ---- transformed weight panels (k-major [k][o]); pad rows (f>=FH) zeroed
        for (int idx = t; idx < FHP * FOUT; idx += NT) {
            int f = idx / FOUT, o = idx - f * FOUT;
            float w0 = 0.f, w1 = 0.f, w2 = 0.f;
            if (f < FH) {
                int fg = ph * FH + f;
                w0 = W[o * (3 * FIN) + fg * 3 + 0];
                w1 = W[o * (3 * FIN) + fg * 3 + 1];
                w2 = W[o * (3 * FIN) + fg * 3 + 2];
            }
            Wl[(0 * FHP + f) * FOUT + o] = w0 - w2;
            Wl[(1 * FHP + f) * FOUT + o] = w1;
            Wl[(2 * FHP + f) * FOUT + o] = 2.f * w2;
        }
        // ---- stage x0 feature slice (own share), pair-major
        if constexpr (FH == 3) {
            float a0 = xin[((size_t)b * V + vloc) * 3 + 0];
            float a1 = xin[((size_t)b * V + vloc) * 3 + 1];
            float a2 = xin[((size_t)b * V + vloc) * 3 + 2];
            float2 p0 = {a0, a1};
            float2 p1 = {a2, 0.f};
            *(float2*)&xs[0 * RS + 2 * vloc] = p0;
            *(float2*)&xs[1 * RS + 2 * vloc] = p1;
        } else {
#pragma unroll
            for (int j = 0; j < FHS / 4; ++j) {
                float4 q = *(const float4*)(xin + ((size_t)b * V + vloc) * FIN + ph * FH + os * FHS + 4 * j);
                float2 pa = {q.x, q.y};
                float2 pb = {q.z, q.w};
                *(float2*)&xs[(fbp + 2 * j + 0) * RS + 2 * vloc] = pa;
                *(float2*)&xs[(fbp + 2 * j + 1) * RS + 2 * vloc] = pb;
            }
        }
        __syncthreads();
        // ---- x1 = L x0  (pairs [0, FHP/2) -> [FHP/2, FHP))
        GATHER(0, FHP / 2)
        __syncthreads();
        // ---- x2raw = L x1  (pairs [FHP/2, FHP) -> [FHP, 3*FHP/2))
        GATHER(FHP / 2, FHP)
        __syncthreads();
        // ---- GEMM accumulate over all PR pairs (K = 3*FHP)
        {
            const int a0w = 8 * vt;
#pragma unroll
            for (int p = 0; p < PR; ++p) {
                float4 q1 = *(const float4*)&xs[p * RS + a0w];
                float4 q2 = *(const float4*)&xs[p * RS + a0w + 4];
                float av0[4] = {q1.x, q1.z, q2.x, q2.z};  // feature 2p
                float av1[4] = {q1.y, q1.w, q2.y, q2.w};  // feature 2p+1
#pragma unroll
                for (int j = 0; j < OW / 4; ++j) {
                    float4 w0v = *(const float4*)&Wl[(2 * p + 0) * FOUT + o0 + 4 * j];
                    float4 w1v = *(const float4*)&Wl[(2 * p + 1) * FOUT + o0 + 4 * j];
#pragma unroll
                    for (int i = 0; i < 4; ++i) {
                        acc[i][4 * j + 0] += av0[i] * w0v.x + av1[i] * w1v.x;
                        acc[i][4 * j + 1] += av0[i] * w0v.y + av1[i] * w1v.y;
                        acc[i][4 * j + 2] += av0[i] * w0v.z + av1[i] * w1v.z;
                        acc[i][4 * j + 3] += av0[i] * w0v.w + av1[i] * w1v.w;
                    }
                }
            }
        }
        __syncthreads();  // protect LDS before next phase overwrites
    }
#undef GATHER

    // ---- epilogue
    if constexpr (POOL == 0) {
#pragma unroll
        for (int i = 0; i < 4; ++i) {
            float* orow = out + ((size_t)b * V + 4 * vt + i) * FOUT + o0;
#pragma unroll
            for (int j = 0; j < OW / 4; ++j) {
                float4 st;
                st.x = acc[i][4 * j + 0] + bias[o0 + 4 * j + 0];
                st.y = acc[i][4 * j + 1] + bias[o0 + 4 * j + 1];
                st.z = acc[i][4 * j + 2] + bias[o0 + 4 * j + 2];
                st.w = acc[i][4 * j + 3] + bias[o0 + 4 * j + 3];
                ((float4*)orow)[j] = st;
            }
        }
    } else {
        float* orow = out + ((size_t)b * (V / 4) + vt) * FOUT + o0;
#pragma unroll
        for (int j = 0; j < OW / 4; ++j) {
            float4 st;
#pragma unroll
            for (int q = 0; q < 4; ++q) {
                int o = 4 * j + q;
                float m = fmaxf(fmaxf(acc[0][o], acc[1][o]), fmaxf(acc[2][o], acc[3][o]));
                ((float*)&st)[q] = m + bias[o0 + o];
            }
            ((float4*)orow)[j] = st;
        }
    }
}

// ---------------- FC1: C[512,512] = A[512,4096] * W[512,4096]^T, split-K=16 ----------------
__global__ __launch_bounds__(256) void k_fc1(const float* __restrict__ A,
                                             const float* __restrict__ W,
                                             float* __restrict__ part) {
    __shared__ float As[16][128];
    __shared__ float Bs[16][128];
    const int tid = threadIdx.x;
    const int bm = blockIdx.x, bn = blockIdx.y, bz = blockIdx.z;
    const int m0 = (tid >> 4) << 3;
    const int n0 = (tid & 15) << 3;
    float acc[8][8];
#pragma unroll
    for (int i = 0; i < 8; ++i)
#pragma unroll
        for (int j = 0; j < 8; ++j) acc[i][j] = 0.f;
    const int r = tid >> 1;
    const int c8 = (tid & 1) << 3;
    const float* Ar = A + (size_t)(bm * 128 + r) * 4096 + bz * 256 + c8;
    const float* Wr = W + (size_t)(bn * 128 + r) * 4096 + bz * 256 + c8;
    for (int kt = 0; kt < 256; kt += 16) {
        float4 a0 = *(const float4*)(Ar + kt);
        float4 a1 = *(const float4*)(Ar + kt + 4);
        float4 w0 = *(const float4*)(Wr + kt);
        float4 w1 = *(const float4*)(Wr + kt + 4);
        __syncthreads();
        As[c8 + 0][r] = a0.x; As[c8 + 1][r] = a0.y; As[c8 + 2][r] = a0.z; As[c8 + 3][r] = a0.w;
        As[c8 + 4][r] = a1.x; As[c8 + 5][r] = a1.y; As[c8 + 6][r] = a1.z; As[c8 + 7][r] = a1.w;
        Bs[c8 + 0][r] = w0.x; Bs[c8 + 1][r] = w0.y; Bs[c8 + 2][r] = w0.z; Bs[c8 + 3][r] = w0.w;
        Bs[c8 + 4][r] = w1.x; Bs[c8 + 5][r] = w1.y; Bs[c8 + 6][r] = w1.z; Bs[c8 + 7][r] = w1.w;
        __syncthreads();
#pragma unroll
        for (int k = 0; k < 16; ++k) {
            float am[8], bn_[8];
            *(float4*)&am[0] = *(const float4*)&As[k][m0];
            *(float4*)&am[4] = *(const float4*)&As[k][m0 + 4];
            *(float4*)&bn_[0] = *(const float4*)&Bs[k][n0];
            *(float4*)&bn_[4] = *(const float4*)&Bs[k][n0 + 4];
#pragma unroll
            for (int i = 0; i < 8; ++i)
#pragma unroll
                for (int j = 0; j < 8; ++j) acc[i][j] += am[i] * bn_[j];
        }
    }
    float* P = part + ((size_t)bz * 512 + bm * 128 + m0) * 512 + bn * 128 + n0;
#pragma unroll
    for (int i = 0; i < 8; ++i) {
        float4 s0 = {acc[i][0], acc[i][1], acc[i][2], acc[i][3]};
        float4 s1 = {acc[i][4], acc[i][5], acc[i][6], acc[i][7]};
        *(float4*)(P + i * 512) = s0;
        *(float4*)(P + i * 512 + 4) = s1;
    }
}

__global__ void k_fc1red(const float* __restrict__ part, const float* __restrict__ bias,
                         float* __restrict__ out) {
    int t = blockIdx.x * 256 + threadIdx.x;  // 512*512
    float s = bias[t & 511];
#pragma unroll
    for (int z = 0; z < 16; ++z) s += part[(size_t)z * 262144 + t];
    out[t] = s;
}

// ---------------- FC2: out[512,63] ----------------
__global__ void k_fc2(const float* __restrict__ X, const float* __restrict__ W,
                      const float* __restrict__ bias, float* __restrict__ out) {
    int b = blockIdx.x, c = threadIdx.x;
    if (c >= 63) return;
    const float4* xr = (const float4*)(X + b * 512);
    const float4* wr = (const float4*)(W + c * 512);
    float s = 0.f;
    for (int k = 0; k < 128; ++k) {
        float4 xv = xr[k], wv = wr[k];
        s += xv.x * wv.x + xv.y * wv.y + xv.z * wv.z + xv.w * wv.w;
    }
    out[b * 63 + c] = s + bias[c];
}

extern "C" void kernel_launch(void* const* d_in, const int* in_sizes, int n_in,
                              void* d_out, int out_size, void* d_ws, size_t ws_size,
                              hipStream_t stream) {
    const float* x = (const float*)d_in[0];
    const int* rows0 = (const int*)d_in[1];
    const int* cols0 = (const int*)d_in[2];
    const float* vals0 = (const float*)d_in[3];
    const int* rows1 = (const int*)d_in[4];
    const int* cols1 = (const int*)d_in[5];
    const float* vals1 = (const float*)d_in[6];
    const float* W0 = (const float*)d_in[7];  const float* b0 = (const float*)d_in[8];
    const float* W1 = (const float*)d_in[9];  const float* b1 = (const float*)d_in[10];
    const float* W2 = (const float*)d_in[11]; const float* b2 = (const float*)d_in[12];
    const float* W3 = (const float*)d_in[13]; const float* b3 = (const float*)d_in[14];
    const float* fcW1 = (const float*)d_in[15]; const float* fcb1 = (const float*)d_in[16];
    const float* fcW2 = (const float*)d_in[17]; const float* fcb2 = (const float*)d_in[18];
    float* out = (float*)d_out;

    float* wsf = (float*)d_ws;
    // small region
    int* off0 = (int*)(wsf + 0);          // 1025
    int* off1 = (int*)(wsf + 1088);       // 257
    int* deg0 = (int*)(wsf + 1408);       // 1024
    int* deg1 = (int*)(wsf + 2432);       // 256
    int2* epk0 = (int2*)(wsf + 4096);     // 8192 int2 -> [4096, 20480)
    int2* epk1 = (int2*)(wsf + 20480);    // 2048 int2 -> [20480, 24576)

    float* A1  = wsf + 65536;             // 16,777,216  [B,1024,32]
    float* P1  = A1 + 16777216;           //  4,194,304  [B,256,32]
    float* A3  = P1 + 4194304;            //  8,388,608  [B,256,64]
    float* FCB = A3 + 8388608;            //  2,097,152  [B,4096]
    float* PART = FCB + 2097152;          //  4,194,304  [16,512,512]
    float* FC1O = PART + 4194304;         //    262,144  [512,512]
    (void)in_sizes; (void)n_in; (void)out_size; (void)ws_size;

    hipMemsetAsync(wsf + 1408, 0, 1280 * 4, stream);
    k_deg<<<E0 / 256, 256, 0, stream>>>(rows0, E0, deg0);
    k_deg<<<E1 / 256, 256, 0, stream>>>(rows1, E1, deg1);
    k_scan<<<1, 1024, 0, stream>>>(deg0, off0, V0);
    k_scan<<<1, 1024, 0, stream>>>(deg1, off1, V1);
    k_fillp<<<E0 / 256, 256, 0, stream>>>(rows0, cols0, vals0, E0, off0, epk0);
    k_fillp<<<E1 / 256, 256, 0, stream>>>(rows1, cols1, vals1, E1, off1, epk1);

    // conv1: level0, 3->32 (padded to 4), 1024 thr, LDS ~51 KB
    k_conv<V0, 3, 3, 32, 1, 0, 1><<<BB, 1024, 0, stream>>>(x, W0, b0, A1, off0, epk0);
    // conv2+pool: level0, 32->32, FH=8, 1024 thr, LDS ~100 KB
    k_conv<V0, 32, 8, 32, 1, 1, 1><<<BB, 1024, 0, stream>>>(A1, W1, b1, P1, off0, epk0);
    // conv3: level1, 32->64, OS=2, 512 thr, 512 blocks, LDS ~31 KB
    k_conv<V1, 32, 8, 64, 2, 0, 2><<<BB, 512, 0, stream>>>(P1, W2, b2, A3, off1, epk1);
    // conv4+pool: level1, 64->64, OS=2, 512 thr, 512 blocks, LDS ~31 KB
    k_conv<V1, 64, 8, 64, 2, 1, 2><<<BB, 512, 0, stream>>>(A3, W3, b3, FCB, off1, epk1);

    // head (FCB is [B, 4096] in reference order)
    k_fc1<<<dim3(4, 4, 16), 256, 0, stream>>>(FCB, fcW1, PART);
    k_fc1red<<<1024, 256, 0, stream>>>(PART, fcb1, FC1O);
    k_fc2<<<BB, 64, 0, stream>>>(FC1O, fcW2, fcb2, out);
}

// Round 15
// 439.911 us; speedup vs baseline: 4.7816x; 4.7816x over previous
//
#include <hip/hip_runtime.h>

#define BB 512
#define V0 1024
#define V1 256
#define E0 8192
#define E1 2048

// ---------------- CSR build (deterministic), both levels per launch ----------------
__global__ void k_deg2(const int* __restrict__ rows0, const int* __restrict__ rows1,
                       int* __restrict__ deg0, int* __restrict__ deg1) {
    int bb = blockIdx.x;
    if (bb < E0 / 256) {
        int t = bb * 256 + threadIdx.x;
        atomicAdd(&deg0[rows0[t]], 1);
    } else {
        int t = (bb - E0 / 256) * 256 + threadIdx.x;
        atomicAdd(&deg1[rows1[t]], 1);
    }
}

__global__ void k_scan2(const int* __restrict__ deg0, int* __restrict__ off0,
                        const int* __restrict__ deg1, int* __restrict__ off1) {
    __shared__ int s[1024];
    const int* deg = (blockIdx.x == 0) ? deg0 : deg1;
    int* off = (blockIdx.x == 0) ? off0 : off1;
    int V = (blockIdx.x == 0) ? V0 : V1;
    int t = threadIdx.x;
    s[t] = (t < V) ? deg[t] : 0;
    __syncthreads();
    for (int d = 1; d < 1024; d <<= 1) {
        int val = (t >= d) ? s[t - d] : 0;
        __syncthreads();
        s[t] += val;
        __syncthreads();
    }
    if (t < V) off[t + 1] = s[t];
    if (t == 0) off[0] = 0;
}

// stable fill: edge e goes to off[row] + (#earlier edges with same row); packed (col,val)
__global__ void k_fillp2(const int* __restrict__ rows0, const int* __restrict__ cols0,
                         const float* __restrict__ vals0, const int* __restrict__ off0,
                         int2* __restrict__ epk0,
                         const int* __restrict__ rows1, const int* __restrict__ cols1,
                         const float* __restrict__ vals1, const int* __restrict__ off1,
                         int2* __restrict__ epk1) {
    __shared__ int rs[256];
    const bool lv0 = (blockIdx.x < E0 / 256);
    const int rb = lv0 ? blockIdx.x : blockIdx.x - E0 / 256;
    const int* rows = lv0 ? rows0 : rows1;
    const int* cols = lv0 ? cols0 : cols1;
    const float* vals = lv0 ? vals0 : vals1;
    const int* off = lv0 ? off0 : off1;
    int2* epk = lv0 ? epk0 : epk1;
    const int E = lv0 ? E0 : E1;

    int e = rb * 256 + threadIdx.x;
    int r = rows[e];
    int rank = 0;
    for (int c0 = 0; c0 <= rb; ++c0) {
        __syncthreads();
        int idx = c0 * 256 + threadIdx.x;
        rs[threadIdx.x] = (idx < E) ? rows[idx] : -2;
        __syncthreads();
        int lim = e - c0 * 256;
        if (lim > 256) lim = 256;
        for (int j = 0; j < lim; ++j) rank += (rs[j] == r) ? 1 : 0;
    }
    int p = off[r] + rank;
    epk[p] = make_int2(cols[e], __float_as_int(vals[e]));
}

// ---------------- fused cheby conv, batch-major, feature-major LDS (padded) ----------------
// Template = R11/R13 (verified 474us): feature-major slab, Wl LDS panels, packed int2
// edges, 2-deep prefetch, acc[4][OW] microtile, OS output/feature split for level-1.
template <int V, int FIN, int FH, int FOUT, int OS, int POOL, int MW>
__global__ __launch_bounds__(V * OS, MW) void k_conv(
    const float* __restrict__ xin, const float* __restrict__ W,
    const float* __restrict__ bias, float* __restrict__ out,
    const int* __restrict__ off, const int2* __restrict__ epk) {
    constexpr int NPH = FIN / FH;
    constexpr int FHS = FH / OS;        // features gathered per thread
    constexpr int OW = FOUT / (4 * OS); // outputs per thread
    constexpr int NT = V * OS;
    constexpr int NCP = V + 4;          // padded column stride (16B aligned)
    __shared__ float xsA[3 * FH * NCP];
    __shared__ float Wl[3 * FH * FOUT];

    const int t = threadIdx.x;
    const int b = blockIdx.x;
    const int os = (OS == 1) ? 0 : (t / V);
    const int vloc = (OS == 1) ? t : (t - os * V);
    const int vt = vloc >> 2;
    const int ot = vloc & 3;
    const int o0 = os * (FOUT / OS) + ot * OW;
    const int fb = os * FHS;

    const int s0 = off[vloc];
    const int e0 = off[vloc + 1];

    float acc[4][OW];
#pragma unroll
    for (int i = 0; i < 4; ++i)
#pragma unroll
        for (int o = 0; o < OW; ++o) acc[i][o] = 0.f;

// gather pass with 2-deep edge prefetch: r = L * slab[RB+fb..) -> slab[ROUT+fb..) at own col
#define GATHER(RB, ROUT)                                                      \
    {                                                                         \
        float r_[FHS];                                                        \
        _Pragma("unroll") for (int f = 0; f < FHS; ++f) r_[f] = 0.f;          \
        int2 e_ = epk[s0];                                                    \
        for (int p = s0; p < e0; ++p) {                                       \
            int2 cur_ = e_;                                                   \
            if (p + 1 < e0) e_ = epk[p + 1];                                  \
            float w_ = __int_as_float(cur_.y);                                \
            int c_ = cur_.x;                                                  \
            _Pragma("unroll") for (int f = 0; f < FHS; ++f)                   \
                r_[f] += w_ * xsA[((RB) + fb + f) * NCP + c_];                \
        }                                                                     \
        _Pragma("unroll") for (int f = 0; f < FHS; ++f)                       \
            xsA[((ROUT) + fb + f) * NCP + vloc] = r_[f];                      \
    }

    for (int ph = 0; ph < NPH; ++ph) {
        // ---- transformed weight panels for this feature slice (k-major [k][o])
        for (int idx = t; idx < FH * FOUT; idx += NT) {
            int f = idx / FOUT, o = idx - f * FOUT;
            int fg = ph * FH + f;
            float w0 = W[o * (3 * FIN) + fg * 3 + 0];
            float w1 = W[o * (3 * FIN) + fg * 3 + 1];
            float w2 = W[o * (3 * FIN) + fg * 3 + 2];
            Wl[f * FOUT + o] = w0 - w2;
            Wl[(FH + f) * FOUT + o] = w1;
            Wl[(2 * FH + f) * FOUT + o] = 2.f * w2;
        }
        // ---- stage x0 feature slice (own share), feature-major (padded stride)
        if constexpr (FH == 3) {
#pragma unroll
            for (int f = 0; f < 3; ++f)
                xsA[f * NCP + vloc] = xin[((size_t)b * V + vloc) * 3 + f];
        } else {
#pragma unroll
            for (int j = 0; j < FHS / 4; ++j) {
                float4 q = *(const float4*)(xin + ((size_t)b * V + vloc) * FIN + ph * FH + fb + 4 * j);
                xsA[(fb + 4 * j + 0) * NCP + vloc] = q.x;
                xsA[(fb + 4 * j + 1) * NCP + vloc] = q.y;
                xsA[(fb + 4 * j + 2) * NCP + vloc] = q.z;
                xsA[(fb + 4 * j + 3) * NCP + vloc] = q.w;
            }
        }
        __syncthreads();
        // ---- x1 = L x0
        GATHER(0, FH)
        __syncthreads();
        // ---- x2raw = L x1
        GATHER(FH, 2 * FH)
        __syncthreads();
        // ---- GEMM accumulate: K = 3*FH (A spans all features; W from LDS b128)
        {
            const int a0 = 4 * vt;
#pragma unroll 4
            for (int k = 0; k < 3 * FH; ++k) {
                float4 a = *(const float4*)&xsA[k * NCP + a0];
                float av[4] = {a.x, a.y, a.z, a.w};
#pragma unroll
                for (int j = 0; j < OW / 4; ++j) {
                    float4 wv = *(const float4*)&Wl[k * FOUT + o0 + 4 * j];
#pragma unroll
                    for (int i = 0; i < 4; ++i) {
                        acc[i][4 * j + 0] += av[i] * wv.x;
                        acc[i][4 * j + 1] += av[i] * wv.y;
                        acc[i][4 * j + 2] += av[i] * wv.z;
                        acc[i][4 * j + 3] += av[i] * wv.w;
                    }
                }
            }
        }
        __syncthreads();  // protect LDS before next phase overwrites
    }
#undef GATHER

    // ---- epilogue
    if constexpr (POOL == 0) {
#pragma unroll
        for (int i = 0; i < 4; ++i) {
            float* orow = out + ((size_t)b * V + 4 * vt + i) * FOUT + o0;
#pragma unroll
            for (int j = 0; j < OW / 4; ++j) {
                float4 st;
                st.x = acc[i][4 * j + 0] + bias[o0 + 4 * j + 0];
                st.y = acc[i][4 * j + 1] + bias[o0 + 4 * j + 1];
                st.z = acc[i][4 * j + 2] + bias[o0 + 4 * j + 2];
                st.w = acc[i][4 * j + 3] + bias[o0 + 4 * j + 3];
                ((float4*)orow)[j] = st;
            }
        }
    } else {
        float* orow = out + ((size_t)b * (V / 4) + vt) * FOUT + o0;
#pragma unroll
        for (int j = 0; j < OW / 4; ++j) {
            float4 st;
#pragma unroll
            for (int q = 0; q < 4; ++q) {
                int o = 4 * j + q;
                float m = fmaxf(fmaxf(acc[0][o], acc[1][o]), fmaxf(acc[2][o], acc[3][o]));
                ((float*)&st)[q] = m + bias[o0 + o];
            }
            ((float4*)orow)[j] = st;
        }
    }
}

// ---------------- FC1: C[512,512] = A[512,4096] * W[512,4096]^T, split-K=16 ----------------
__global__ __launch_bounds__(256) void k_fc1(const float* __restrict__ A,
                                             const float* __restrict__ W,
                                             float* __restrict__ part) {
    __shared__ float As[16][128];
    __shared__ float Bs[16][128];
    const int tid = threadIdx.x;
    const int bm = blockIdx.x, bn = blockIdx.y, bz = blockIdx.z;
    const int m0 = (tid >> 4) << 3;
    const int n0 = (tid & 15) << 3;
    float acc[8][8];
#pragma unroll
    for (int i = 0; i < 8; ++i)
#pragma unroll
        for (int j = 0; j < 8; ++j) acc[i][j] = 0.f;
    const int r = tid >> 1;
    const int c8 = (tid & 1) << 3;
    const float* Ar = A + (size_t)(bm * 128 + r) * 4096 + bz * 256 + c8;
    const float* Wr = W + (size_t)(bn * 128 + r) * 4096 + bz * 256 + c8;
    for (int kt = 0; kt < 256; kt += 16) {
        float4 a0 = *(const float4*)(Ar + kt);
        float4 a1 = *(const float4*)(Ar + kt + 4);
        float4 w0 = *(const float4*)(Wr + kt);
        float4 w1 = *(const float4*)(Wr + kt + 4);
        __syncthreads();
        As[c8 + 0][r] = a0.x; As[c8 + 1][r] = a0.y; As[c8 + 2][r] = a0.z; As[c8 + 3][r] = a0.w;
        As[c8 + 4][r] = a1.x; As[c8 + 5][r] = a1.y; As[c8 + 6][r] = a1.z; As[c8 + 7][r] = a1.w;
        Bs[c8 + 0][r] = w0.x; Bs[c8 + 1][r] = w0.y; Bs[c8 + 2][r] = w0.z; Bs[c8 + 3][r] = w0.w;
        Bs[c8 + 4][r] = w1.x; Bs[c8 + 5][r] = w1.y; Bs[c8 + 6][r] = w1.z; Bs[c8 + 7][r] = w1.w;
        __syncthreads();
#pragma unroll
        for (int k = 0; k < 16; ++k) {
            float am[8], bn_[8];
            *(float4*)&am[0] = *(const float4*)&As[k][m0];
            *(float4*)&am[4] = *(const float4*)&As[k][m0 + 4];
            *(float4*)&bn_[0] = *(const float4*)&Bs[k][n0];
            *(float4*)&bn_[4] = *(const float4*)&Bs[k][n0 + 4];
#pragma unroll
            for (int i = 0; i < 8; ++i)
#pragma unroll
                for (int j = 0; j < 8; ++j) acc[i][j] += am[i] * bn_[j];
        }
    }
    float* P = part + ((size_t)bz * 512 + bm * 128 + m0) * 512 + bn * 128 + n0;
#pragma unroll
    for (int i = 0; i < 8; ++i) {
        float4 s0 = {acc[i][0], acc[i][1], acc[i][2], acc[i][3]};
        float4 s1 = {acc[i][4], acc[i][5], acc[i][6], acc[i][7]};
        *(float4*)(P + i * 512) = s0;
        *(float4*)(P + i * 512 + 4) = s1;
    }
}

__global__ void k_fc1red(const float* __restrict__ part, const float* __restrict__ bias,
                         float* __restrict__ out) {
    int t = blockIdx.x * 256 + threadIdx.x;  // 512*512
    float s = bias[t & 511];
#pragma unroll
    for (int z = 0; z < 16; ++z) s += part[(size_t)z * 262144 + t];
    out[t] = s;
}

// ---------------- FC2: out[512,63], split-K over 4 slices ----------------
__global__ __launch_bounds__(256) void k_fc2(const float* __restrict__ X,
                                             const float* __restrict__ W,
                                             const float* __restrict__ bias,
                                             float* __restrict__ out) {
    __shared__ float red[256];
    const int b = blockIdx.x;
    const int j = threadIdx.x;
    const int c = j & 63;
    const int ks = j >> 6;  // 0..3, each covers 128 floats (32 float4)
    float s = 0.f;
    if (c < 63) {
        const float4* xr = (const float4*)(X + b * 512) + ks * 32;
        const float4* wr = (const float4*)(W + c * 512) + ks * 32;
        for (int k = 0; k < 32; ++k) {
            float4 xv = xr[k], wv = wr[k];
            s += xv.x * wv.x + xv.y * wv.y + xv.z * wv.z + xv.w * wv.w;
        }
    }
    red[j] = s;
    __syncthreads();
    if (ks == 0 && c < 63)
        out[b * 63 + c] = red[c] + red[64 + c] + red[128 + c] + red[192 + c] + bias[c];
}

extern "C" void kernel_launch(void* const* d_in, const int* in_sizes, int n_in,
                              void* d_out, int out_size, void* d_ws, size_t ws_size,
                              hipStream_t stream) {
    const float* x = (const float*)d_in[0];
    const int* rows0 = (const int*)d_in[1];
    const int* cols0 = (const int*)d_in[2];
    const float* vals0 = (const float*)d_in[3];
    const int* rows1 = (const int*)d_in[4];
    const int* cols1 = (const int*)d_in[5];
    const float* vals1 = (const float*)d_in[6];
    const float* W0 = (const float*)d_in[7];  const float* b0 = (const float*)d_in[8];
    const float* W1 = (const float*)d_in[9];  const float* b1 = (const float*)d_in[10];
    const float* W2 = (const float*)d_in[11]; const float* b2 = (const float*)d_in[12];
    const float* W3 = (const float*)d_in[13]; const float* b3 = (const float*)d_in[14];
    const float* fcW1 = (const float*)d_in[15]; const float* fcb1 = (const float*)d_in[16];
    const float* fcW2 = (const float*)d_in[17]; const float* fcb2 = (const float*)d_in[18];
    float* out = (float*)d_out;

    float* wsf = (float*)d_ws;
    // small region
    int* off0 = (int*)(wsf + 0);          // 1025
    int* off1 = (int*)(wsf + 1088);       // 257
    int* deg0 = (int*)(wsf + 1408);       // 1024
    int* deg1 = (int*)(wsf + 2432);       // 256
    int2* epk0 = (int2*)(wsf + 4096);     // 8192 int2 -> [4096, 20480)
    int2* epk1 = (int2*)(wsf + 20480);    // 2048 int2 -> [20480, 24576)

    float* A1  = wsf + 65536;             // 16,777,216  [B,1024,32]
    float* P1  = A1 + 16777216;           //  4,194,304  [B,256,32]
    float* A3  = P1 + 4194304;            //  8,388,608  [B,256,64]
    float* FCB = A3 + 8388608;            //  2,097,152  [B,4096]
    float* PART = FCB + 2097152;          //  4,194,304  [16,512,512]
    float* FC1O = PART + 4194304;         //    262,144  [512,512]
    (void)in_sizes; (void)n_in; (void)out_size; (void)ws_size;

    hipMemsetAsync(wsf + 1408, 0, 1280 * 4, stream);
    k_deg2<<<E0 / 256 + E1 / 256, 256, 0, stream>>>(rows0, rows1, deg0, deg1);
    k_scan2<<<2, 1024, 0, stream>>>(deg0, off0, deg1, off1);
    k_fillp2<<<E0 / 256 + E1 / 256, 256, 0, stream>>>(rows0, cols0, vals0, off0, epk0,
                                                      rows1, cols1, vals1, off1, epk1);

    // conv1: level0, 3->32             1024 thr (identical to R13)
    k_conv<V0, 3, 3, 32, 1, 0, 1><<<BB, 1024, 0, stream>>>(x, W0, b0, A1, off0, epk0);
    // conv2+pool: level0, 32->32, FH=8, 1024 thr (identical to R13)
    k_conv<V0, 32, 8, 32, 1, 1, 1><<<BB, 1024, 0, stream>>>(A1, W1, b1, P1, off0, epk0);
    // conv3: level1, 32->64, FH=16 (2 phases), OS=2, 512 thr, LDS ~62 KB
    k_conv<V1, 32, 16, 64, 2, 0, 2><<<BB, 512, 0, stream>>>(P1, W2, b2, A3, off1, epk1);
    // conv4+pool: level1, 64->64, FH=16 (4 phases), OS=2, 512 thr, LDS ~62 KB
    k_conv<V1, 64, 16, 64, 2, 1, 2><<<BB, 512, 0, stream>>>(A3, W3, b3, FCB, off1, epk1);

    // head (FCB is [B, 4096] in reference order)
    k_fc1<<<dim3(4, 4, 16), 256, 0, stream>>>(FCB, fcW1, PART);
    k_fc1red<<<1024, 256, 0, stream>>>(PART, fcb1, FC1O);
    k_fc2<<<BB, 256, 0, stream>>>(FC1O, fcW2, fcb2, out);
}